// Round 1
// baseline (3997.881 us; speedup 1.0000x reference)
//
#include <hip/hip_runtime.h>
#include <math.h>

#define B_  256
#define S_  200
#define F_  10
#define T_  100
#define E_  128
#define H_  256
#define G4  1024   // 4*H
#define P1_ 512
#define P2_ 128

__device__ __forceinline__ float sigf(float x) { return 1.0f / (1.0f + expf(-x)); }

__global__ __launch_bounds__(256) void k_bsum(const float* __restrict__ bi,
                                              const float* __restrict__ bh,
                                              float* __restrict__ bs) {
    int i = blockIdx.x * 256 + threadIdx.x;
    if (i < G4) bs[i] = bi[i] + bh[i];
}

// one block per (b,s); 128 threads = one e-dim each
__global__ __launch_bounds__(128) void k_gather(const int* __restrict__ x,
                                                const float* __restrict__ emb,
                                                float* __restrict__ e) {
    int bs = blockIdx.x;
    int t  = threadIdx.x;
    const int* xr = x + (long)bs * F_;
    float acc = 0.f;
    #pragma unroll
    for (int f = 0; f < F_; ++f) acc += emb[(long)xr[f] * E_ + t];
    e[(long)bs * E_ + t] = acc * (1.0f / F_);
}

// C[m,n] = act( sum_k a(m,k)*b(k,n) + bias[n] + rowAdd[(m/rowAddDiv)*N + n] )
// a(m,k) = A[(m/rowDiv)*sOuter + (m%rowDiv)*sInner + k]
// BT=1: Bm is (N,K) row-major; BT=0: Bm is (K,N) row-major.
// Requires M%64==0, N%64==0, K%32==0.
template<int BT, int ACT>
__global__ __launch_bounds__(256) void k_gemm(
    const float* __restrict__ A, int rowDiv, long sOuter, long sInner,
    const float* __restrict__ Bm,
    const float* __restrict__ bias,
    const float* __restrict__ rowAdd, int rowAddDiv,
    float* __restrict__ C, int M, int N, int K)
{
    __shared__ float Al[64][33];
    __shared__ float Bl[2112];   // BT: [64][33] ; BN: [32][65]
    int tid = threadIdx.x;
    int n0 = blockIdx.x * 64;
    int m0 = blockIdx.y * 64;

    int cA = tid & 31;
    long rb[8];
    #pragma unroll
    for (int i = 0; i < 8; ++i) {
        int r = (tid >> 5) + 8 * i;
        int m = m0 + r;
        rb[i] = (long)(m / rowDiv) * sOuter + (long)(m % rowDiv) * sInner;
    }
    int tr = tid >> 4, tc = tid & 15;
    float acc[4][4] = {};
    int nk = K >> 5;
    for (int kc = 0; kc < nk; ++kc) {
        #pragma unroll
        for (int i = 0; i < 8; ++i)
            Al[(tid >> 5) + 8 * i][cA] = A[rb[i] + kc * 32 + cA];
        if (BT) {
            #pragma unroll
            for (int i = 0; i < 8; ++i) {
                int lin = tid + 256 * i;
                int n = lin >> 5, k = lin & 31;
                Bl[n * 33 + k] = Bm[(long)(n0 + n) * K + kc * 32 + k];
            }
        } else {
            #pragma unroll
            for (int i = 0; i < 8; ++i) {
                int lin = tid + 256 * i;
                int k = lin >> 6, n = lin & 63;
                Bl[k * 65 + n] = Bm[(long)(kc * 32 + k) * N + n0 + n];
            }
        }
        __syncthreads();
        #pragma unroll
        for (int k = 0; k < 32; ++k) {
            float a[4], b[4];
            #pragma unroll
            for (int i = 0; i < 4; ++i) a[i] = Al[tr * 4 + i][k];
            #pragma unroll
            for (int j = 0; j < 4; ++j) b[j] = BT ? Bl[(tc * 4 + j) * 33 + k]
                                                  : Bl[k * 65 + tc * 4 + j];
            #pragma unroll
            for (int i = 0; i < 4; ++i)
                #pragma unroll
                for (int j = 0; j < 4; ++j)
                    acc[i][j] += a[i] * b[j];
        }
        __syncthreads();
    }
    #pragma unroll
    for (int i = 0; i < 4; ++i) {
        int m = m0 + tr * 4 + i;
        #pragma unroll
        for (int j = 0; j < 4; ++j) {
            int n = n0 + tc * 4 + j;
            float v = acc[i][j];
            if (bias)   v += bias[n];
            if (rowAdd) v += rowAdd[(long)(m / rowAddDiv) * N + n];
            if (ACT == 1) v = fmaxf(v, 0.f);
            C[(long)m * N + n] = v;
        }
    }
}

// fused per-step: g_hh = h_prev @ W_hh^T (block owns 32 b-rows x 32 j-cols x all 4 gates),
// then cell update. grid = (H/32, B/32).
__global__ __launch_bounds__(256) void k_lstm_step(
    const float* __restrict__ h_prev, float* __restrict__ h_next,
    float* __restrict__ c, const float* __restrict__ Xg,
    const float* __restrict__ W_hh, int t)
{
    __shared__ float hA[32][257];
    __shared__ float Wl[128 * 33];   // reused post-loop as gates[32][stride 129]
    int tid = threadIdx.x;
    int j0 = blockIdx.x * 32;
    int b0 = blockIdx.y * 32;
    for (int i = tid; i < 32 * 256; i += 256)
        hA[i >> 8][i & 255] = h_prev[(long)(b0 + (i >> 8)) * H_ + (i & 255)];
    int tr = tid >> 5, tc = tid & 31;
    float acc[4][4] = {};
    for (int kc = 0; kc < 8; ++kc) {
        #pragma unroll
        for (int i = 0; i < 16; ++i) {
            int lin = tid + 256 * i;
            int rr = lin >> 5, kk = lin & 31;
            int gate = rr >> 5, jj = rr & 31;
            Wl[rr * 33 + kk] = W_hh[(long)(gate * H_ + j0 + jj) * H_ + kc * 32 + kk];
        }
        __syncthreads();
        #pragma unroll
        for (int k = 0; k < 32; ++k) {
            float a[4], b[4];
            #pragma unroll
            for (int i = 0; i < 4; ++i) a[i] = hA[tr * 4 + i][kc * 32 + k];
            #pragma unroll
            for (int j = 0; j < 4; ++j) b[j] = Wl[(tc * 4 + j) * 33 + k];
            #pragma unroll
            for (int i = 0; i < 4; ++i)
                #pragma unroll
                for (int j = 0; j < 4; ++j)
                    acc[i][j] += a[i] * b[j];
        }
        __syncthreads();
    }
    // stash gates in LDS so each thread can grab all 4 gates of its cells
    #pragma unroll
    for (int i = 0; i < 4; ++i)
        #pragma unroll
        for (int j = 0; j < 4; ++j)
            Wl[(tr * 4 + i) * 129 + tc * 4 + j] = acc[i][j];
    __syncthreads();
    #pragma unroll
    for (int q = 0; q < 4; ++q) {
        int ci = tid + 256 * q;
        int bl = ci >> 5, jl = ci & 31;
        const float* xg = Xg + ((long)(b0 + bl) * T_ + t) * G4 + j0 + jl;
        float gi = Wl[bl * 129 +  0 + jl] + xg[0];
        float gf = Wl[bl * 129 + 32 + jl] + xg[H_];
        float gg = Wl[bl * 129 + 64 + jl] + xg[2 * H_];
        float go = Wl[bl * 129 + 96 + jl] + xg[3 * H_];
        long off = (long)(b0 + bl) * H_ + j0 + jl;
        float cn = sigf(gf) * c[off] + sigf(gi) * tanhf(gg);
        c[off] = cn;
        h_next[off] = sigf(go) * tanhf(cn);
    }
}

__global__ __launch_bounds__(256) void k_dec_cell(const float* __restrict__ G,
                                                  const float* __restrict__ cN,
                                                  float* __restrict__ hdec) {
    long idx = (long)blockIdx.x * 256 + threadIdx.x;
    int m = (int)(idx >> 8);
    int j = (int)(idx & 255);
    int b = m / T_;
    const float* g = G + (long)m * G4 + j;
    float gi = g[0], gf = g[H_], gg = g[2 * H_], go = g[3 * H_];
    float cv = sigf(gf) * cN[(long)b * H_ + j] + sigf(gi) * tanhf(gg);
    hdec[idx] = sigf(go) * tanhf(cv);
}

// out[m] = sigmoid(dot(z2[m,:128], W3) + b3); one wave per row, 4 rows/block
__global__ __launch_bounds__(256) void k_mlp3(const float* __restrict__ z2,
                                              const float* __restrict__ W3,
                                              const float* __restrict__ b3,
                                              float* __restrict__ out) {
    int wave = threadIdx.x >> 6, lane = threadIdx.x & 63;
    int m = blockIdx.x * 4 + wave;
    const float* zr = z2 + (long)m * P2_;
    float s = zr[lane] * W3[lane] + zr[64 + lane] * W3[64 + lane];
    #pragma unroll
    for (int off = 32; off > 0; off >>= 1) s += __shfl_down(s, off);
    if (lane == 0) out[m] = sigf(s + b3[0]);
}

extern "C" void kernel_launch(void* const* d_in, const int* in_sizes, int n_in,
                              void* d_out, int out_size, void* d_ws, size_t ws_size,
                              hipStream_t stream)
{
    const int*   x    = (const int*)d_in[0];
    const float* emb  = (const float*)d_in[1];
    const float* W_ih = (const float*)d_in[2];
    const float* W_hh = (const float*)d_in[3];
    const float* b_ih = (const float*)d_in[4];
    const float* b_hh = (const float*)d_in[5];
    const float* W1   = (const float*)d_in[6];
    const float* b1   = (const float*)d_in[7];
    const float* W2   = (const float*)d_in[8];
    const float* b2   = (const float*)d_in[9];
    const float* W3   = (const float*)d_in[10];
    const float* b3   = (const float*)d_in[11];
    float* out = (float*)d_out;

    float* ws    = (float*)d_ws;
    float* e     = ws;                          // B*S*E     = 6,553,600 f
    float* Xg    = e + (long)B_ * S_ * E_;      // B*T*4H    = 26,214,400 f
    float* bsum  = Xg + (long)B_ * T_ * G4;     // 1024 f
    float* h0    = bsum + G4;                   // B*H
    float* h1    = h0 + B_ * H_;                // B*H
    float* cbuf  = h1 + B_ * H_;                // B*H
    float* hhdec = cbuf + B_ * H_;              // B*4H = 262,144 f
    // reuse after their producers/consumers are done:
    float* hdec = e;                            // B*T*H == B*S*E (same size)
    float* z1   = Xg;                           // B*T*P1 = 13,107,200 f
    float* z2   = Xg + (long)B_ * T_ * P1_;     // B*T*P2 =  3,276,800 f

    hipMemsetAsync(h0,   0, (size_t)B_ * H_ * sizeof(float), stream);
    hipMemsetAsync(cbuf, 0, (size_t)B_ * H_ * sizeof(float), stream);

    k_bsum<<<4, 256, 0, stream>>>(b_ih, b_hh, bsum);
    k_gather<<<B_ * S_, 128, 0, stream>>>(x, emb, e);

    // Xg = e_hist @ W_ih^T + bsum   (M=B*T, N=4H, K=E)
    k_gemm<1, 0><<<dim3(G4 / 64, (B_ * T_) / 64), 256, 0, stream>>>(
        e, T_, (long)S_ * E_, (long)E_, W_ih, bsum, nullptr, 1,
        Xg, B_ * T_, G4, E_);

    // sequential scan, ping-pong h buffers
    float* hp = h0; float* hn = h1;
    for (int t = 0; t < T_; ++t) {
        k_lstm_step<<<dim3(H_ / 32, B_ / 32), 256, 0, stream>>>(hp, hn, cbuf, Xg, W_hh, t);
        float* tmp = hp; hp = hn; hn = tmp;
    }

    // hhdec = hN @ W_hh^T + bsum   (M=B, N=4H, K=H)
    k_gemm<1, 0><<<dim3(G4 / 64, B_ / 64), 256, 0, stream>>>(
        hp, B_, 0L, (long)H_, W_hh, bsum, nullptr, 1,
        hhdec, B_, G4, H_);

    // Gdec = e_tgt @ W_ih^T + hhdec[b]   (into Xg buffer)
    k_gemm<1, 0><<<dim3(G4 / 64, (B_ * T_) / 64), 256, 0, stream>>>(
        e + T_ * E_, T_, (long)S_ * E_, (long)E_, W_ih, nullptr, hhdec, T_,
        Xg, B_ * T_, G4, E_);

    // decode cell -> hdec (reuses e buffer)
    k_dec_cell<<<(B_ * T_ * H_) / 256, 256, 0, stream>>>(Xg, cbuf, hdec);

    // z1 = relu(hdec @ W1 + b1)   (M=B*T, N=P1, K=H) -> Xg buffer
    k_gemm<0, 1><<<dim3(P1_ / 64, (B_ * T_) / 64), 256, 0, stream>>>(
        hdec, B_ * T_, 0L, (long)H_, W1, b1, nullptr, 1,
        z1, B_ * T_, P1_, H_);

    // z2 = relu(z1 @ W2 + b2)   (M=B*T, N=P2, K=P1)
    k_gemm<0, 1><<<dim3(P2_ / 64, (B_ * T_) / 64), 256, 0, stream>>>(
        z1, B_ * T_, 0L, (long)P1_, W2, b2, nullptr, 1,
        z2, B_ * T_, P2_, P1_);

    // out = sigmoid(z2 . W3 + b3)
    k_mlp3<<<(B_ * T_) / 4, 256, 0, stream>>>(z2, W3, b3, out);
}

// Round 2
// 1480.740 us; speedup vs baseline: 2.6999x; 2.6999x over previous
//
#include <hip/hip_runtime.h>
#include <math.h>

#define B_  256
#define S_  200
#define F_  10
#define T_  100
#define E_  128
#define H_  256
#define G4  1024   // 4*H
#define P1_ 512
#define P2_ 128

__device__ __forceinline__ float sigf(float x) { return 1.0f / (1.0f + expf(-x)); }

__global__ __launch_bounds__(256) void k_bsum(const float* __restrict__ bi,
                                              const float* __restrict__ bh,
                                              float* __restrict__ bs) {
    int i = blockIdx.x * 256 + threadIdx.x;
    if (i < G4) bs[i] = bi[i] + bh[i];
}

// W (1024 x 256) -> WT (256 x 1024)
__global__ __launch_bounds__(256) void k_transpose(const float* __restrict__ W,
                                                   float* __restrict__ WT) {
    __shared__ float tle[32][33];
    int k0 = blockIdx.x * 32;
    int g0 = blockIdx.y * 32;
    int c = threadIdx.x & 31, r0 = threadIdx.x >> 5;
    #pragma unroll
    for (int i = 0; i < 4; ++i)
        tle[r0 + i * 8][c] = W[(long)(g0 + r0 + i * 8) * 256 + k0 + c];
    __syncthreads();
    #pragma unroll
    for (int i = 0; i < 4; ++i)
        WT[(long)(k0 + r0 + i * 8) * G4 + g0 + c] = tle[c][r0 + i * 8];
}

// one block per (b,s); 128 threads = one e-dim each
__global__ __launch_bounds__(128) void k_gather(const int* __restrict__ x,
                                                const float* __restrict__ emb,
                                                float* __restrict__ e) {
    int bs = blockIdx.x;
    int t  = threadIdx.x;
    const int* xr = x + (long)bs * F_;
    float acc = 0.f;
    #pragma unroll
    for (int f = 0; f < F_; ++f) acc += emb[(long)xr[f] * E_ + t];
    e[(long)bs * E_ + t] = acc * (1.0f / F_);
}

// C[m,n] = act( sum_k a(m,k)*b(k,n) + bias[n] + rowAdd[(m/rowAddDiv)*N + n] )
// a(m,k) = A[(m/rowDiv)*sOuter + (m%rowDiv)*sInner + k]
// BT=1: Bm is (N,K) row-major; BT=0: Bm is (K,N) row-major.
template<int BT, int ACT>
__global__ __launch_bounds__(256) void k_gemm(
    const float* __restrict__ A, int rowDiv, long sOuter, long sInner,
    const float* __restrict__ Bm,
    const float* __restrict__ bias,
    const float* __restrict__ rowAdd, int rowAddDiv,
    float* __restrict__ C, int M, int N, int K)
{
    __shared__ float Al[64][33];
    __shared__ float Bl[2112];   // BT: [64][33] ; BN: [32][65]
    int tid = threadIdx.x;
    int n0 = blockIdx.x * 64;
    int m0 = blockIdx.y * 64;

    int cA = tid & 31;
    long rb[8];
    #pragma unroll
    for (int i = 0; i < 8; ++i) {
        int r = (tid >> 5) + 8 * i;
        int m = m0 + r;
        rb[i] = (long)(m / rowDiv) * sOuter + (long)(m % rowDiv) * sInner;
    }
    int tr = tid >> 4, tc = tid & 15;
    float acc[4][4] = {};
    int nk = K >> 5;
    for (int kc = 0; kc < nk; ++kc) {
        #pragma unroll
        for (int i = 0; i < 8; ++i)
            Al[(tid >> 5) + 8 * i][cA] = A[rb[i] + kc * 32 + cA];
        if (BT) {
            #pragma unroll
            for (int i = 0; i < 8; ++i) {
                int lin = tid + 256 * i;
                int n = lin >> 5, k = lin & 31;
                Bl[n * 33 + k] = Bm[(long)(n0 + n) * K + kc * 32 + k];
            }
        } else {
            #pragma unroll
            for (int i = 0; i < 8; ++i) {
                int lin = tid + 256 * i;
                int k = lin >> 6, n = lin & 63;
                Bl[k * 65 + n] = Bm[(long)(kc * 32 + k) * N + n0 + n];
            }
        }
        __syncthreads();
        #pragma unroll
        for (int k = 0; k < 32; ++k) {
            float a[4], b[4];
            #pragma unroll
            for (int i = 0; i < 4; ++i) a[i] = Al[tr * 4 + i][k];
            #pragma unroll
            for (int j = 0; j < 4; ++j) b[j] = BT ? Bl[(tc * 4 + j) * 33 + k]
                                                  : Bl[k * 65 + tc * 4 + j];
            #pragma unroll
            for (int i = 0; i < 4; ++i)
                #pragma unroll
                for (int j = 0; j < 4; ++j)
                    acc[i][j] += a[i] * b[j];
        }
        __syncthreads();
    }
    #pragma unroll
    for (int i = 0; i < 4; ++i) {
        int m = m0 + tr * 4 + i;
        #pragma unroll
        for (int j = 0; j < 4; ++j) {
            int n = n0 + tc * 4 + j;
            float v = acc[i][j];
            if (bias)   v += bias[n];
            if (rowAdd) v += rowAdd[(long)(m / rowAddDiv) * N + n];
            if (ACT == 1) v = fmaxf(v, 0.f);
            C[(long)m * N + n] = v;
        }
    }
}

// Persistent batch-parallel LSTM scan: one block per batch row, loops all T steps.
// WT is W_hh transposed to (K=256) x (G=1024). h,c live in LDS/registers.
// 1024 threads = 4 k-quarters x 256 g-quads.
__global__ __launch_bounds__(1024) void k_lstm_scan(
    const float* __restrict__ Xg, const float* __restrict__ WT,
    float* __restrict__ hN, float* __restrict__ cN)
{
    __shared__ __align__(16) float h_s[H_];
    __shared__ __align__(16) float red[4 * G4];
    __shared__ __align__(16) float g_s[G4];
    int tid = threadIdx.x;
    int b   = blockIdx.x;
    int kq  = tid >> 8;          // k-quarter 0..3
    int s4  = (tid & 255) * 4;   // g-quad base 0..1020
    float c_r = 0.f;
    if (tid < H_) h_s[tid] = 0.f;
    __syncthreads();
    const float* xgb = Xg + (long)b * T_ * G4;
    const float* wq  = WT + (long)(kq * 64) * G4 + s4;
    for (int t = 0; t < T_; ++t) {
        float a0 = 0.f, a1 = 0.f, a2 = 0.f, a3 = 0.f;
        #pragma unroll 8
        for (int i = 0; i < 64; ++i) {
            float4 w = *(const float4*)(wq + (long)i * G4);
            float hv = h_s[kq * 64 + i];
            a0 += w.x * hv; a1 += w.y * hv; a2 += w.z * hv; a3 += w.w * hv;
        }
        *(float4*)&red[kq * G4 + s4] = make_float4(a0, a1, a2, a3);
        __syncthreads();
        g_s[tid] = red[tid] + red[G4 + tid] + red[2 * G4 + tid] + red[3 * G4 + tid];
        __syncthreads();
        if (tid < H_) {
            const float* xg = xgb + (long)t * G4 + tid;
            float gi = g_s[tid]          + xg[0];
            float gf = g_s[H_ + tid]     + xg[H_];
            float gg = g_s[2 * H_ + tid] + xg[2 * H_];
            float go = g_s[3 * H_ + tid] + xg[3 * H_];
            float cn = sigf(gf) * c_r + sigf(gi) * tanhf(gg);
            c_r = cn;
            h_s[tid] = sigf(go) * tanhf(cn);
        }
        __syncthreads();
    }
    if (tid < H_) {
        hN[(long)b * H_ + tid] = h_s[tid];
        cN[(long)b * H_ + tid] = c_r;
    }
}

__global__ __launch_bounds__(256) void k_dec_cell(const float* __restrict__ G,
                                                  const float* __restrict__ cNb,
                                                  float* __restrict__ hdec) {
    long idx = (long)blockIdx.x * 256 + threadIdx.x;
    int m = (int)(idx >> 8);
    int j = (int)(idx & 255);
    int b = m / T_;
    const float* g = G + (long)m * G4 + j;
    float gi = g[0], gf = g[H_], gg = g[2 * H_], go = g[3 * H_];
    float cv = sigf(gf) * cNb[(long)b * H_ + j] + sigf(gi) * tanhf(gg);
    hdec[idx] = sigf(go) * tanhf(cv);
}

// out[m] = sigmoid(dot(z2[m,:128], W3) + b3); one wave per row, 4 rows/block
__global__ __launch_bounds__(256) void k_mlp3(const float* __restrict__ z2,
                                              const float* __restrict__ W3,
                                              const float* __restrict__ b3,
                                              float* __restrict__ out) {
    int wave = threadIdx.x >> 6, lane = threadIdx.x & 63;
    int m = blockIdx.x * 4 + wave;
    const float* zr = z2 + (long)m * P2_;
    float s = zr[lane] * W3[lane] + zr[64 + lane] * W3[64 + lane];
    #pragma unroll
    for (int off = 32; off > 0; off >>= 1) s += __shfl_down(s, off);
    if (lane == 0) out[m] = sigf(s + b3[0]);
}

extern "C" void kernel_launch(void* const* d_in, const int* in_sizes, int n_in,
                              void* d_out, int out_size, void* d_ws, size_t ws_size,
                              hipStream_t stream)
{
    const int*   x    = (const int*)d_in[0];
    const float* emb  = (const float*)d_in[1];
    const float* W_ih = (const float*)d_in[2];
    const float* W_hh = (const float*)d_in[3];
    const float* b_ih = (const float*)d_in[4];
    const float* b_hh = (const float*)d_in[5];
    const float* W1   = (const float*)d_in[6];
    const float* b1   = (const float*)d_in[7];
    const float* W2   = (const float*)d_in[8];
    const float* b2   = (const float*)d_in[9];
    const float* W3   = (const float*)d_in[10];
    const float* b3   = (const float*)d_in[11];
    float* out = (float*)d_out;

    float* ws    = (float*)d_ws;
    float* e     = ws;                          // B*S*E   = 6,553,600 f
    float* Xg    = e + (long)B_ * S_ * E_;      // B*T*4H  = 26,214,400 f
    float* bsum  = Xg + (long)B_ * T_ * G4;     // 1024 f
    float* hN    = bsum + G4;                   // B*H = 65,536 f
    float* cN    = hN + B_ * H_;                // B*H
    float* hhdec = cN + B_ * H_;                // B*4H = 262,144 f
    float* WT    = hhdec;                       // same slot: WT live only until scan ends,
                                                // hhdec written only after scan (stream-ordered)
    // reuse after their producers/consumers are done:
    float* hdec = e;                            // B*T*H == B*S*E (same size)
    float* z1   = Xg;                           // B*T*P1
    float* z2   = Xg + (long)B_ * T_ * P1_;     // B*T*P2

    k_bsum<<<4, 256, 0, stream>>>(b_ih, b_hh, bsum);
    k_transpose<<<dim3(8, 32), 256, 0, stream>>>(W_hh, WT);
    k_gather<<<B_ * S_, 128, 0, stream>>>(x, emb, e);

    // Xg = e_hist @ W_ih^T + bsum   (M=B*T, N=4H, K=E)
    k_gemm<1, 0><<<dim3(G4 / 64, (B_ * T_) / 64), 256, 0, stream>>>(
        e, T_, (long)S_ * E_, (long)E_, W_ih, bsum, nullptr, 1,
        Xg, B_ * T_, G4, E_);

    // persistent scan: 256 blocks (one per batch row), no inter-block sync
    k_lstm_scan<<<B_, 1024, 0, stream>>>(Xg, WT, hN, cN);

    // hhdec = hN @ W_hh^T + bsum   (M=B, N=4H, K=H)  -- overwrites WT slot
    k_gemm<1, 0><<<dim3(G4 / 64, B_ / 64), 256, 0, stream>>>(
        hN, B_, 0L, (long)H_, W_hh, bsum, nullptr, 1,
        hhdec, B_, G4, H_);

    // Gdec = e_tgt @ W_ih^T + hhdec[b]   (into Xg buffer)
    k_gemm<1, 0><<<dim3(G4 / 64, (B_ * T_) / 64), 256, 0, stream>>>(
        e + T_ * E_, T_, (long)S_ * E_, (long)E_, W_ih, nullptr, hhdec, T_,
        Xg, B_ * T_, G4, E_);

    // decode cell -> hdec (reuses e buffer)
    k_dec_cell<<<(B_ * T_ * H_) / 256, 256, 0, stream>>>(Xg, cN, hdec);

    // z1 = relu(hdec @ W1 + b1)   (M=B*T, N=P1, K=H) -> Xg buffer
    k_gemm<0, 1><<<dim3(P1_ / 64, (B_ * T_) / 64), 256, 0, stream>>>(
        hdec, B_ * T_, 0L, (long)H_, W1, b1, nullptr, 1,
        z1, B_ * T_, P1_, H_);

    // z2 = relu(z1 @ W2 + b2)   (M=B*T, N=P2, K=P1)
    k_gemm<0, 1><<<dim3(P2_ / 64, (B_ * T_) / 64), 256, 0, stream>>>(
        z1, B_ * T_, 0L, (long)P1_, W2, b2, nullptr, 1,
        z2, B_ * T_, P2_, P1_);

    // out = sigmoid(z2 . W3 + b3)
    k_mlp3<<<(B_ * T_) / 4, 256, 0, stream>>>(z2, W3, b3, out);
}

// Round 3
// 1272.466 us; speedup vs baseline: 3.1418x; 1.1637x over previous
//
#include <hip/hip_runtime.h>
#include <hip/hip_bf16.h>
#include <math.h>

#define B_  256
#define S_  200
#define F_  10
#define T_  100
#define E_  128
#define H_  256
#define G4  1024   // 4*H
#define P1_ 512
#define P2_ 128

__device__ __forceinline__ float sigf(float x) { return 1.0f / (1.0f + expf(-x)); }
__device__ __forceinline__ float bflo(unsigned u) { return __uint_as_float(u << 16); }
__device__ __forceinline__ float bfhi(unsigned u) { return __uint_as_float(u & 0xffff0000u); }

__global__ __launch_bounds__(256) void k_bsum(const float* __restrict__ bi,
                                              const float* __restrict__ bh,
                                              float* __restrict__ bs) {
    int i = blockIdx.x * 256 + threadIdx.x;
    if (i < G4) bs[i] = bi[i] + bh[i];
}

// W_hh (1024 x 256) -> WTb (256 x 1024) in bf16 (RNE)
__global__ __launch_bounds__(256) void k_transpose_bf16(const float* __restrict__ W,
                                                        ushort* __restrict__ WTb) {
    __shared__ float tle[32][33];
    int k0 = blockIdx.x * 32;
    int g0 = blockIdx.y * 32;
    int c = threadIdx.x & 31, r0 = threadIdx.x >> 5;
    #pragma unroll
    for (int i = 0; i < 4; ++i)
        tle[r0 + i * 8][c] = W[(long)(g0 + r0 + i * 8) * 256 + k0 + c];
    __syncthreads();
    #pragma unroll
    for (int i = 0; i < 4; ++i) {
        __hip_bfloat16 v = __float2bfloat16(tle[c][r0 + i * 8]);
        WTb[(long)(k0 + r0 + i * 8) * G4 + g0 + c] = *(ushort*)&v;
    }
}

// one block per (b,s); 128 threads = one e-dim each
__global__ __launch_bounds__(128) void k_gather(const int* __restrict__ x,
                                                const float* __restrict__ emb,
                                                float* __restrict__ e) {
    int bs = blockIdx.x;
    int t  = threadIdx.x;
    const int* xr = x + (long)bs * F_;
    float acc = 0.f;
    #pragma unroll
    for (int f = 0; f < F_; ++f) acc += emb[(long)xr[f] * E_ + t];
    e[(long)bs * E_ + t] = acc * (1.0f / F_);
}

// C[m,n] = act( sum_k a(m,k)*b(k,n) + bias[n] + rowAdd[(m/rowAddDiv)*N + n] )
// a(m,k) = A[(m/rowDiv)*sOuter + (m%rowDiv)*sInner + k]
// BT=1: Bm is (N,K) row-major; BT=0: Bm is (K,N) row-major.
// Block tile 64m x 128n, per-thread 8x4. Requires M%64==0, N%128==0, K%32==0.
template<int BT, int ACT>
__global__ __launch_bounds__(256) void k_gemm(
    const float* __restrict__ A, int rowDiv, long sOuter, long sInner,
    const float* __restrict__ Bm,
    const float* __restrict__ bias,
    const float* __restrict__ rowAdd, int rowAddDiv,
    float* __restrict__ C, int M, int N, int K)
{
    __shared__ float Al[32 * 66];    // [k][m], stride 66
    __shared__ float Bl[32 * 130];   // [k][n], stride 130
    int tid = threadIdx.x;
    int n0 = blockIdx.x * 128;
    int m0 = blockIdx.y * 64;

    int cA = tid & 31;      // k within tile for A staging
    int rA = tid >> 5;      // m base (8 rows, stride 8)
    long rb[8];
    #pragma unroll
    for (int i = 0; i < 8; ++i) {
        int m = m0 + rA + 8 * i;
        rb[i] = (long)(m / rowDiv) * sOuter + (long)(m % rowDiv) * sInner;
    }
    int tr = tid >> 5;      // 0..7 -> m-sub block of 8
    int tc = tid & 31;      // 0..31 -> n-quad
    float acc[8][4] = {};
    int nk = K >> 5;
    for (int kc = 0; kc < nk; ++kc) {
        #pragma unroll
        for (int i = 0; i < 8; ++i)
            Al[cA * 66 + rA + 8 * i] = A[rb[i] + kc * 32 + cA];
        if (BT) {
            #pragma unroll
            for (int i = 0; i < 16; ++i) {
                int lin = tid + 256 * i;
                int n = lin >> 5, k = lin & 31;
                Bl[k * 130 + n] = Bm[(long)(n0 + n) * K + kc * 32 + k];
            }
        } else {
            #pragma unroll
            for (int i = 0; i < 16; ++i) {
                int lin = tid + 256 * i;
                int k = lin >> 7, n = lin & 127;
                Bl[k * 130 + n] = Bm[(long)(kc * 32 + k) * N + n0 + n];
            }
        }
        __syncthreads();
        #pragma unroll 4
        for (int k = 0; k < 32; ++k) {
            float a_[8], b_[4];
            *(float2*)&a_[0] = *(float2*)&Al[k * 66 + tr * 8];
            *(float2*)&a_[2] = *(float2*)&Al[k * 66 + tr * 8 + 2];
            *(float2*)&a_[4] = *(float2*)&Al[k * 66 + tr * 8 + 4];
            *(float2*)&a_[6] = *(float2*)&Al[k * 66 + tr * 8 + 6];
            *(float2*)&b_[0] = *(float2*)&Bl[k * 130 + tc * 4];
            *(float2*)&b_[2] = *(float2*)&Bl[k * 130 + tc * 4 + 2];
            #pragma unroll
            for (int i = 0; i < 8; ++i)
                #pragma unroll
                for (int j = 0; j < 4; ++j)
                    acc[i][j] += a_[i] * b_[j];
        }
        __syncthreads();
    }
    #pragma unroll
    for (int i = 0; i < 8; ++i) {
        int m = m0 + tr * 8 + i;
        int n = n0 + tc * 4;
        float4 v;
        float* vp = &v.x;
        #pragma unroll
        for (int j = 0; j < 4; ++j) {
            float t = acc[i][j];
            if (bias)   t += bias[n + j];
            if (rowAdd) t += rowAdd[(long)(m / rowAddDiv) * N + n + j];
            if (ACT == 1) t = fmaxf(t, 0.f);
            vp[j] = t;
        }
        *(float4*)&C[(long)m * N + n] = v;
    }
}

// Persistent batch-parallel LSTM scan, bf16 weights.
// WTb is W_hh transposed to (K=256) x (G=1024), bf16.
// 1024 threads = 8 k-groups (32 k each) x 128 g-octets.
__global__ __launch_bounds__(1024) void k_lstm_scan(
    const float* __restrict__ Xg, const ushort* __restrict__ WTb,
    float* __restrict__ hN, float* __restrict__ cN)
{
    __shared__ __align__(16) float h_s[H_];
    __shared__ __align__(16) float red[8 * G4];   // 32 KB
    __shared__ __align__(16) float act_s[G4];
    int tid = threadIdx.x;
    int b   = blockIdx.x;
    int kg  = tid >> 7;          // k-group 0..7
    int go  = (tid & 127) * 8;   // g-octet base
    float c_r = 0.f;
    if (tid < H_) h_s[tid] = 0.f;
    __syncthreads();
    const float* xgb = Xg + (long)b * T_ * G4;
    const ushort* wq = WTb + (long)(kg * 32) * G4 + go;
    for (int t = 0; t < T_; ++t) {
        float a0 = 0.f, a1 = 0.f, a2 = 0.f, a3 = 0.f;
        float a4 = 0.f, a5 = 0.f, a6 = 0.f, a7 = 0.f;
        #pragma unroll 8
        for (int i = 0; i < 32; ++i) {
            uint4 w = *(const uint4*)(wq + (long)i * G4);
            float hv = h_s[kg * 32 + i];
            a0 += bflo(w.x) * hv; a1 += bfhi(w.x) * hv;
            a2 += bflo(w.y) * hv; a3 += bfhi(w.y) * hv;
            a4 += bflo(w.z) * hv; a5 += bfhi(w.z) * hv;
            a6 += bflo(w.w) * hv; a7 += bfhi(w.w) * hv;
        }
        *(float4*)&red[kg * G4 + go]     = make_float4(a0, a1, a2, a3);
        *(float4*)&red[kg * G4 + go + 4] = make_float4(a4, a5, a6, a7);
        __syncthreads();
        float g = red[tid] + red[G4 + tid] + red[2 * G4 + tid] + red[3 * G4 + tid]
                + red[4 * G4 + tid] + red[5 * G4 + tid] + red[6 * G4 + tid] + red[7 * G4 + tid]
                + xgb[(long)t * G4 + tid];
        act_s[tid] = ((tid >> 8) == 2) ? tanhf(g) : sigf(g);
        __syncthreads();
        if (tid < H_) {
            float cn = act_s[H_ + tid] * c_r + act_s[tid] * act_s[2 * H_ + tid];
            c_r = cn;
            h_s[tid] = act_s[3 * H_ + tid] * tanhf(cn);
        }
        __syncthreads();
    }
    if (tid < H_) {
        hN[(long)b * H_ + tid] = h_s[tid];
        cN[(long)b * H_ + tid] = c_r;
    }
}

__global__ __launch_bounds__(256) void k_dec_cell(const float* __restrict__ G,
                                                  const float* __restrict__ cNb,
                                                  float* __restrict__ hdec) {
    long idx = (long)blockIdx.x * 256 + threadIdx.x;
    int m = (int)(idx >> 8);
    int j = (int)(idx & 255);
    int b = m / T_;
    const float* g = G + (long)m * G4 + j;
    float gi = g[0], gf = g[H_], gg = g[2 * H_], go = g[3 * H_];
    float cv = sigf(gf) * cNb[(long)b * H_ + j] + sigf(gi) * tanhf(gg);
    hdec[idx] = sigf(go) * tanhf(cv);
}

// out[m] = sigmoid(dot(z2[m,:128], W3) + b3); one wave per row, 4 rows/block
__global__ __launch_bounds__(256) void k_mlp3(const float* __restrict__ z2,
                                              const float* __restrict__ W3,
                                              const float* __restrict__ b3,
                                              float* __restrict__ out) {
    int wave = threadIdx.x >> 6, lane = threadIdx.x & 63;
    int m = blockIdx.x * 4 + wave;
    const float* zr = z2 + (long)m * P2_;
    float s = zr[lane] * W3[lane] + zr[64 + lane] * W3[64 + lane];
    #pragma unroll
    for (int off = 32; off > 0; off >>= 1) s += __shfl_down(s, off);
    if (lane == 0) out[m] = sigf(s + b3[0]);
}

extern "C" void kernel_launch(void* const* d_in, const int* in_sizes, int n_in,
                              void* d_out, int out_size, void* d_ws, size_t ws_size,
                              hipStream_t stream)
{
    const int*   x    = (const int*)d_in[0];
    const float* emb  = (const float*)d_in[1];
    const float* W_ih = (const float*)d_in[2];
    const float* W_hh = (const float*)d_in[3];
    const float* b_ih = (const float*)d_in[4];
    const float* b_hh = (const float*)d_in[5];
    const float* W1   = (const float*)d_in[6];
    const float* b1   = (const float*)d_in[7];
    const float* W2   = (const float*)d_in[8];
    const float* b2   = (const float*)d_in[9];
    const float* W3   = (const float*)d_in[10];
    const float* b3   = (const float*)d_in[11];
    float* out = (float*)d_out;

    float* ws    = (float*)d_ws;
    float* e     = ws;                          // B*S*E   = 6,553,600 f
    float* Xg    = e + (long)B_ * S_ * E_;      // B*T*4H  = 26,214,400 f
    float* bsum  = Xg + (long)B_ * T_ * G4;     // 1024 f
    float* hN    = bsum + G4;                   // B*H
    float* cN    = hN + B_ * H_;                // B*H
    float* hhdec = cN + B_ * H_;                // B*4H = 262,144 f (1 MB)
    ushort* WTb  = (ushort*)hhdec;              // 512 KB; live only until scan ends,
                                                // hhdec written after scan (stream-ordered)
    // reuse after their producers/consumers are done:
    float* hdec = e;                            // B*T*H == B*S*E (same size)
    float* z1   = Xg;                           // B*T*P1
    float* z2   = Xg + (long)B_ * T_ * P1_;     // B*T*P2

    k_bsum<<<4, 256, 0, stream>>>(b_ih, b_hh, bsum);
    k_transpose_bf16<<<dim3(8, 32), 256, 0, stream>>>(W_hh, WTb);
    k_gather<<<B_ * S_, 128, 0, stream>>>(x, emb, e);

    // Xg = e_hist @ W_ih^T + bsum   (M=B*T, N=4H, K=E)
    k_gemm<1, 0><<<dim3(G4 / 128, (B_ * T_) / 64), 256, 0, stream>>>(
        e, T_, (long)S_ * E_, (long)E_, W_ih, bsum, nullptr, 1,
        Xg, B_ * T_, G4, E_);

    // persistent scan: 256 blocks (one per batch row), no inter-block sync
    k_lstm_scan<<<B_, 1024, 0, stream>>>(Xg, WTb, hN, cN);

    // hhdec = hN @ W_hh^T + bsum   (M=B, N=4H, K=H)  -- overwrites WTb slot
    k_gemm<1, 0><<<dim3(G4 / 128, B_ / 64), 256, 0, stream>>>(
        hN, B_, 0L, (long)H_, W_hh, bsum, nullptr, 1,
        hhdec, B_, G4, H_);

    // Gdec = e_tgt @ W_ih^T + hhdec[b]   (into Xg buffer)
    k_gemm<1, 0><<<dim3(G4 / 128, (B_ * T_) / 64), 256, 0, stream>>>(
        e + T_ * E_, T_, (long)S_ * E_, (long)E_, W_ih, nullptr, hhdec, T_,
        Xg, B_ * T_, G4, E_);

    // decode cell -> hdec (reuses e buffer)
    k_dec_cell<<<(B_ * T_ * H_) / 256, 256, 0, stream>>>(Xg, cN, hdec);

    // z1 = relu(hdec @ W1 + b1)   (M=B*T, N=P1, K=H) -> Xg buffer
    k_gemm<0, 1><<<dim3(P1_ / 128, (B_ * T_) / 64), 256, 0, stream>>>(
        hdec, B_ * T_, 0L, (long)H_, W1, b1, nullptr, 1,
        z1, B_ * T_, P1_, H_);

    // z2 = relu(z1 @ W2 + b2)   (M=B*T, N=P2, K=P1)
    k_gemm<0, 1><<<dim3(P2_ / 128, (B_ * T_) / 64), 256, 0, stream>>>(
        z1, B_ * T_, 0L, (long)P1_, W2, b2, nullptr, 1,
        z2, B_ * T_, P2_, P1_);

    // out = sigmoid(z2 . W3 + b3)
    k_mlp3<<<(B_ * T_) / 4, 256, 0, stream>>>(z2, W3, b3, out);
}

// Round 4
// 783.193 us; speedup vs baseline: 5.1046x; 1.6247x over previous
//
#include <hip/hip_runtime.h>
#include <hip/hip_bf16.h>
#include <math.h>

#define B_  256
#define S_  200
#define F_  10
#define T_  100
#define E_  128
#define H_  256
#define G4  1024   // 4*H
#define P1_ 512
#define P2_ 128

typedef __attribute__((ext_vector_type(8))) short short8;
typedef __attribute__((ext_vector_type(4))) float f32x4;

__device__ __forceinline__ float sigf(float x) { return 1.0f / (1.0f + expf(-x)); }
__device__ __forceinline__ float bflo(unsigned u) { return __uint_as_float(u << 16); }
__device__ __forceinline__ float bfhi(unsigned u) { return __uint_as_float(u & 0xffff0000u); }
__device__ __forceinline__ ushort f2bf(float f) {
    __hip_bfloat16 v = __float2bfloat16(f);
    return *(ushort*)&v;
}

__global__ __launch_bounds__(256) void k_bsum(const float* __restrict__ bi,
                                              const float* __restrict__ bh,
                                              float* __restrict__ bs) {
    int i = blockIdx.x * 256 + threadIdx.x;
    if (i < G4) bs[i] = bi[i] + bh[i];
}

// W (R x C) f32 -> WT (C x R) bf16. grid (C/32, R/32), 256 thr.
__global__ __launch_bounds__(256) void k_tr_bf16(const float* __restrict__ W,
                                                 ushort* __restrict__ WT,
                                                 int R, int C) {
    __shared__ float t[32][33];
    int c0 = blockIdx.x * 32, r0 = blockIdx.y * 32;
    int lc = threadIdx.x & 31, lr = threadIdx.x >> 5;
    #pragma unroll
    for (int i = 0; i < 4; ++i)
        t[lr + 8 * i][lc] = W[(long)(r0 + lr + 8 * i) * C + c0 + lc];
    __syncthreads();
    #pragma unroll
    for (int i = 0; i < 4; ++i)
        WT[(long)(c0 + lr + 8 * i) * R + r0 + lc] = f2bf(t[lc][lr + 8 * i]);
}

__global__ __launch_bounds__(256) void k_cvt_bf16(const float* __restrict__ W,
                                                  ushort* __restrict__ O, int n) {
    int i = blockIdx.x * 256 + threadIdx.x;
    if (i < n) O[i] = f2bf(W[i]);
}

// one block per (b,s); 128 threads = one e-dim each; bf16 out
__global__ __launch_bounds__(128) void k_gather(const int* __restrict__ x,
                                                const float* __restrict__ emb,
                                                ushort* __restrict__ e) {
    int bs = blockIdx.x;
    int t  = threadIdx.x;
    const int* xr = x + (long)bs * F_;
    float acc = 0.f;
    #pragma unroll
    for (int f = 0; f < F_; ++f) acc += emb[(long)xr[f] * E_ + t];
    e[(long)bs * E_ + t] = f2bf(acc * (1.0f / F_));
}

// ---------------- bf16 MFMA GEMM ----------------
// C[m,n] = act( sum_k a(m,k)*b(k,n) + bias[n] + rowAdd[(m/rowAddDiv)*N + n] )
// a(m,k) = A[(m/rowDiv)*sOuter + (m%rowDiv)*sInner + k]   (bf16)
// Bm: (N,K) row-major bf16. Tile 128x128, 4 waves (2x2), BK=32.
// Requires M%128==0, N%128==0, K%32==0.
template<int ACT, int OUTBF>
__global__ __launch_bounds__(256) void k_gemm_mfma(
    const ushort* __restrict__ A, int rowDiv, long sOuter, long sInner,
    const ushort* __restrict__ Bm,
    const float* __restrict__ bias,
    const float* __restrict__ rowAdd, int rowAddDiv,
    void* __restrict__ Cout, int N, int K)
{
    constexpr int LDT = 40;                 // 32 k + 8 pad (bf16 units)
    __shared__ ushort Al[128 * LDT];
    __shared__ ushort Bl[128 * LDT];
    int tid = threadIdx.x;
    int n0 = blockIdx.x * 128;
    int m0 = blockIdx.y * 128;

    int rA = tid >> 2, qA = tid & 3;        // staging: row, 8-bf16 quarter
    int m_lo = m0 + rA, m_hi = m_lo + 64;
    long a0 = (long)(m_lo / rowDiv) * sOuter + (long)(m_lo % rowDiv) * sInner + qA * 8;
    long a1 = (long)(m_hi / rowDiv) * sOuter + (long)(m_hi % rowDiv) * sInner + qA * 8;
    const ushort* b0p = Bm + (long)(n0 + rA) * K + qA * 8;
    const ushort* b1p = Bm + (long)(n0 + rA + 64) * K + qA * 8;

    int lane = tid & 63, wave = tid >> 6;
    int wr = wave >> 1, wc = wave & 1;      // wave tile (wr*64, wc*64)
    int lrow = lane & 15, lkh = lane >> 4;  // frag row/col, k-half

    const f32x4 fz = {0.f, 0.f, 0.f, 0.f};
    f32x4 acc[4][4];
    #pragma unroll
    for (int i = 0; i < 4; ++i)
        #pragma unroll
        for (int j = 0; j < 4; ++j) acc[i][j] = fz;

    int nk = K >> 5;
    for (int kc = 0; kc < nk; ++kc) {
        uint4 va0 = *(const uint4*)(A + a0 + kc * 32);
        uint4 va1 = *(const uint4*)(A + a1 + kc * 32);
        uint4 vb0 = *(const uint4*)(b0p + kc * 32);
        uint4 vb1 = *(const uint4*)(b1p + kc * 32);
        *(uint4*)&Al[rA * LDT + qA * 8]        = va0;
        *(uint4*)&Al[(rA + 64) * LDT + qA * 8] = va1;
        *(uint4*)&Bl[rA * LDT + qA * 8]        = vb0;
        *(uint4*)&Bl[(rA + 64) * LDT + qA * 8] = vb1;
        __syncthreads();
        short8 af[4], bfr[4];
        #pragma unroll
        for (int mi = 0; mi < 4; ++mi)
            af[mi] = *(const short8*)&Al[(wr * 64 + mi * 16 + lrow) * LDT + lkh * 8];
        #pragma unroll
        for (int ni = 0; ni < 4; ++ni)
            bfr[ni] = *(const short8*)&Bl[(wc * 64 + ni * 16 + lrow) * LDT + lkh * 8];
        #pragma unroll
        for (int mi = 0; mi < 4; ++mi)
            #pragma unroll
            for (int ni = 0; ni < 4; ++ni)
                acc[mi][ni] = __builtin_amdgcn_mfma_f32_16x16x32_bf16(
                    af[mi], bfr[ni], acc[mi][ni], 0, 0, 0);
        __syncthreads();
    }
    // epilogue: C[row=(lane>>4)*4+r][col=lane&15] per fragment (m89-verified)
    #pragma unroll
    for (int mi = 0; mi < 4; ++mi) {
        #pragma unroll
        for (int r = 0; r < 4; ++r) {
            int m = m0 + wr * 64 + mi * 16 + lkh * 4 + r;
            long rowoff = rowAdd ? (long)(m / rowAddDiv) * N : 0;
            #pragma unroll
            for (int ni = 0; ni < 4; ++ni) {
                int n = n0 + wc * 64 + ni * 16 + lrow;
                float v = acc[mi][ni][r];
                if (bias)   v += bias[n];
                if (rowAdd) v += rowAdd[rowoff + n];
                if (ACT)    v = fmaxf(v, 0.f);
                if (OUTBF) ((ushort*)Cout)[(long)m * N + n] = f2bf(v);
                else       ((float*)Cout)[(long)m * N + n] = v;
            }
        }
    }
}

// ---------------- fp32 GEMM (kept for small hhdec) ----------------
template<int BT, int ACT>
__global__ __launch_bounds__(256) void k_gemm(
    const float* __restrict__ A, int rowDiv, long sOuter, long sInner,
    const float* __restrict__ Bm,
    const float* __restrict__ bias,
    const float* __restrict__ rowAdd, int rowAddDiv,
    float* __restrict__ C, int M, int N, int K)
{
    __shared__ float Al[32 * 66];
    __shared__ float Bl[32 * 130];
    int tid = threadIdx.x;
    int n0 = blockIdx.x * 128;
    int m0 = blockIdx.y * 64;
    int cA = tid & 31;
    int rA = tid >> 5;
    long rb[8];
    #pragma unroll
    for (int i = 0; i < 8; ++i) {
        int m = m0 + rA + 8 * i;
        rb[i] = (long)(m / rowDiv) * sOuter + (long)(m % rowDiv) * sInner;
    }
    int tr = tid >> 5, tc = tid & 31;
    float acc[8][4] = {};
    int nk = K >> 5;
    for (int kc = 0; kc < nk; ++kc) {
        #pragma unroll
        for (int i = 0; i < 8; ++i)
            Al[cA * 66 + rA + 8 * i] = A[rb[i] + kc * 32 + cA];
        if (BT) {
            #pragma unroll
            for (int i = 0; i < 16; ++i) {
                int lin = tid + 256 * i;
                int n = lin >> 5, k = lin & 31;
                Bl[k * 130 + n] = Bm[(long)(n0 + n) * K + kc * 32 + k];
            }
        } else {
            #pragma unroll
            for (int i = 0; i < 16; ++i) {
                int lin = tid + 256 * i;
                int k = lin >> 7, n = lin & 127;
                Bl[k * 130 + n] = Bm[(long)(kc * 32 + k) * N + n0 + n];
            }
        }
        __syncthreads();
        #pragma unroll 4
        for (int k = 0; k < 32; ++k) {
            float a_[8], b_[4];
            *(float2*)&a_[0] = *(float2*)&Al[k * 66 + tr * 8];
            *(float2*)&a_[2] = *(float2*)&Al[k * 66 + tr * 8 + 2];
            *(float2*)&a_[4] = *(float2*)&Al[k * 66 + tr * 8 + 4];
            *(float2*)&a_[6] = *(float2*)&Al[k * 66 + tr * 8 + 6];
            *(float2*)&b_[0] = *(float2*)&Bl[k * 130 + tc * 4];
            *(float2*)&b_[2] = *(float2*)&Bl[k * 130 + tc * 4 + 2];
            #pragma unroll
            for (int i = 0; i < 8; ++i)
                #pragma unroll
                for (int j = 0; j < 4; ++j)
                    acc[i][j] += a_[i] * b_[j];
        }
        __syncthreads();
    }
    #pragma unroll
    for (int i = 0; i < 8; ++i) {
        int m = m0 + tr * 8 + i;
        int n = n0 + tc * 4;
        float4 v;
        float* vp = &v.x;
        #pragma unroll
        for (int j = 0; j < 4; ++j) {
            float t = acc[i][j];
            if (bias)   t += bias[n + j];
            if (rowAdd) t += rowAdd[(long)(m / rowAddDiv) * N + n + j];
            if (ACT == 1) t = fmaxf(t, 0.f);
            vp[j] = t;
        }
        *(float4*)&C[(long)m * N + n] = v;
    }
}

// Persistent batch-parallel LSTM scan, bf16 weights (unchanged from r3).
__global__ __launch_bounds__(1024) void k_lstm_scan(
    const float* __restrict__ Xg, const ushort* __restrict__ WTb,
    float* __restrict__ hN, float* __restrict__ cN)
{
    __shared__ __align__(16) float h_s[H_];
    __shared__ __align__(16) float red[8 * G4];
    __shared__ __align__(16) float act_s[G4];
    int tid = threadIdx.x;
    int b   = blockIdx.x;
    int kg  = tid >> 7;
    int go  = (tid & 127) * 8;
    float c_r = 0.f;
    if (tid < H_) h_s[tid] = 0.f;
    __syncthreads();
    const float* xgb = Xg + (long)b * T_ * G4;
    const ushort* wq = WTb + (long)(kg * 32) * G4 + go;
    for (int t = 0; t < T_; ++t) {
        float a0 = 0.f, a1 = 0.f, a2 = 0.f, a3 = 0.f;
        float a4 = 0.f, a5 = 0.f, a6 = 0.f, a7 = 0.f;
        #pragma unroll 8
        for (int i = 0; i < 32; ++i) {
            uint4 w = *(const uint4*)(wq + (long)i * G4);
            float hv = h_s[kg * 32 + i];
            a0 += bflo(w.x) * hv; a1 += bfhi(w.x) * hv;
            a2 += bflo(w.y) * hv; a3 += bfhi(w.y) * hv;
            a4 += bflo(w.z) * hv; a5 += bfhi(w.z) * hv;
            a6 += bflo(w.w) * hv; a7 += bfhi(w.w) * hv;
        }
        *(float4*)&red[kg * G4 + go]     = make_float4(a0, a1, a2, a3);
        *(float4*)&red[kg * G4 + go + 4] = make_float4(a4, a5, a6, a7);
        __syncthreads();
        float g = red[tid] + red[G4 + tid] + red[2 * G4 + tid] + red[3 * G4 + tid]
                + red[4 * G4 + tid] + red[5 * G4 + tid] + red[6 * G4 + tid] + red[7 * G4 + tid]
                + xgb[(long)t * G4 + tid];
        act_s[tid] = ((tid >> 8) == 2) ? tanhf(g) : sigf(g);
        __syncthreads();
        if (tid < H_) {
            float cn = act_s[H_ + tid] * c_r + act_s[tid] * act_s[2 * H_ + tid];
            c_r = cn;
            h_s[tid] = act_s[3 * H_ + tid] * tanhf(cn);
        }
        __syncthreads();
    }
    if (tid < H_) {
        hN[(long)b * H_ + tid] = h_s[tid];
        cN[(long)b * H_ + tid] = c_r;
    }
}

__global__ __launch_bounds__(256) void k_dec_cell(const float* __restrict__ G,
                                                  const float* __restrict__ cNb,
                                                  ushort* __restrict__ hdec) {
    long idx = (long)blockIdx.x * 256 + threadIdx.x;
    int m = (int)(idx >> 8);
    int j = (int)(idx & 255);
    int b = m / T_;
    const float* g = G + (long)m * G4 + j;
    float gi = g[0], gf = g[H_], gg = g[2 * H_], go = g[3 * H_];
    float cv = sigf(gf) * cNb[(long)b * H_ + j] + sigf(gi) * tanhf(gg);
    hdec[idx] = f2bf(sigf(go) * tanhf(cv));
}

// out[m] = sigmoid(dot(z2[m,:128], W3) + b3); one wave per row, 4 rows/block
__global__ __launch_bounds__(256) void k_mlp3(const float* __restrict__ z2,
                                              const float* __restrict__ W3,
                                              const float* __restrict__ b3,
                                              float* __restrict__ out) {
    int wave = threadIdx.x >> 6, lane = threadIdx.x & 63;
    int m = blockIdx.x * 4 + wave;
    const float* zr = z2 + (long)m * P2_;
    float s = zr[lane] * W3[lane] + zr[64 + lane] * W3[64 + lane];
    #pragma unroll
    for (int off = 32; off > 0; off >>= 1) s += __shfl_down(s, off);
    if (lane == 0) out[m] = sigf(s + b3[0]);
}

extern "C" void kernel_launch(void* const* d_in, const int* in_sizes, int n_in,
                              void* d_out, int out_size, void* d_ws, size_t ws_size,
                              hipStream_t stream)
{
    const int*   x    = (const int*)d_in[0];
    const float* emb  = (const float*)d_in[1];
    const float* W_ih = (const float*)d_in[2];
    const float* W_hh = (const float*)d_in[3];
    const float* b_ih = (const float*)d_in[4];
    const float* b_hh = (const float*)d_in[5];
    const float* W1   = (const float*)d_in[6];
    const float* b1   = (const float*)d_in[7];
    const float* W2   = (const float*)d_in[8];
    const float* b2   = (const float*)d_in[9];
    const float* W3   = (const float*)d_in[10];
    const float* b3   = (const float*)d_in[11];
    float* out = (float*)d_out;

    float* ws = (float*)d_ws;
    ushort* ebf  = (ushort*)ws;                 // B*S*E bf16 = 3,276,800 f-equiv
    float* Xg    = ws + 3276800;                // B*T*G4 = 26,214,400 f
    float* bsum  = Xg + 26214400;               // 1024
    float* hN    = bsum + 1024;                 // 65,536
    float* cN    = hN + 65536;                  // 65,536
    float* hhdec = cN + 65536;                  // 262,144
    ushort* WTb  = (ushort*)(hhdec + 262144);   // 262,144 ush
    ushort* Wihb = WTb + 262144;                // 131,072 ush
    ushort* W1T  = Wihb + 131072;               // 131,072 ush
    ushort* W2T  = W1T + 131072;                // 65,536 ush
    // reuse (stream-ordered):
    ushort* hdec_bf = ebf;                      // after Gdec-GEMM, ebf dead
    ushort* z1b  = (ushort*)Xg;                 // after dec_cell, Xg(Gdec) dead
    float*  z2   = Xg + 6553600;                // after z1b region

    k_bsum<<<4, 256, 0, stream>>>(b_ih, b_hh, bsum);
    k_tr_bf16<<<dim3(8, 32),  256, 0, stream>>>(W_hh, WTb, G4, H_);   // (1024,256)->(256,1024)
    k_tr_bf16<<<dim3(16, 8),  256, 0, stream>>>(W1, W1T, H_, P1_);    // (256,512)->(512,256)
    k_tr_bf16<<<dim3(4, 16),  256, 0, stream>>>(W2, W2T, P1_, P2_);   // (512,128)->(128,512)
    k_cvt_bf16<<<512, 256, 0, stream>>>(W_ih, Wihb, G4 * E_);
    k_gather<<<B_ * S_, 128, 0, stream>>>(x, emb, ebf);

    // Xg = e_hist @ W_ih^T + bsum   (M=B*T, N=4H, K=E)
    k_gemm_mfma<0, 0><<<dim3(G4 / 128, (B_ * T_) / 128), 256, 0, stream>>>(
        ebf, T_, (long)S_ * E_, (long)E_, Wihb, bsum, nullptr, 1,
        Xg, G4, E_);

    // persistent scan
    k_lstm_scan<<<B_, 1024, 0, stream>>>(Xg, WTb, hN, cN);

    // hhdec = hN @ W_hh^T + bsum   (fp32, tiny)
    k_gemm<1, 0><<<dim3(G4 / 128, B_ / 64), 256, 0, stream>>>(
        hN, B_, 0L, (long)H_, W_hh, bsum, nullptr, 1,
        hhdec, B_, G4, H_);

    // Gdec = e_tgt @ W_ih^T + hhdec[b]
    k_gemm_mfma<0, 0><<<dim3(G4 / 128, (B_ * T_) / 128), 256, 0, stream>>>(
        ebf + T_ * E_, T_, (long)S_ * E_, (long)E_, Wihb, nullptr, hhdec, T_,
        Xg, G4, E_);

    // decode cell -> hdec_bf (reuses ebf region)
    k_dec_cell<<<(B_ * T_ * H_) / 256, 256, 0, stream>>>(Xg, cN, hdec_bf);

    // z1 = relu(hdec @ W1 + b1) -> bf16, into Xg region
    k_gemm_mfma<1, 1><<<dim3(P1_ / 128, (B_ * T_) / 128), 256, 0, stream>>>(
        hdec_bf, B_ * T_, 0L, (long)H_, W1T, b1, nullptr, 1,
        z1b, P1_, H_);

    // z2 = relu(z1 @ W2 + b2) -> f32
    k_gemm_mfma<1, 0><<<dim3(P2_ / 128, (B_ * T_) / 128), 256, 0, stream>>>(
        z1b, B_ * T_, 0L, (long)P1_, W2T, b2, nullptr, 1,
        z2, P2_, P1_);

    // out = sigmoid(z2 . W3 + b3)
    k_mlp3<<<(B_ * T_) / 4, 256, 0, stream>>>(z2, W3, b3, out);
}